// Round 10
// baseline (339.505 us; speedup 1.0000x reference)
//
#include <hip/hip_runtime.h>
#include <math.h>

#define S_LEN 2048
#define B_SZ 2
#define NHEAD 16
#define HDIM 64
#define H_DIM 1024
#define M_ROWS (S_LEN * B_SZ)   // 4096
#define LN_EPS 1e-5f
#define KSTR 72                  // attn LDS row stride (shorts)
#define SCL 0.18033688011112042f // 0.125 * log2(e)

typedef __attribute__((ext_vector_type(4))) float f32x4;
typedef __attribute__((ext_vector_type(8))) short short8;
typedef __attribute__((ext_vector_type(8))) unsigned short u16x8;
typedef __attribute__((ext_vector_type(4))) unsigned short u16x4;
typedef __attribute__((ext_vector_type(2))) unsigned short u16x2;

typedef __attribute__((address_space(3))) unsigned int lds_u32;
typedef const __attribute__((address_space(1))) unsigned int glb_u32;

#define ASM_VMCNT(N) asm volatile("s_waitcnt vmcnt(" #N ")" ::: "memory")

__device__ __forceinline__ float bf2f(unsigned short u) {
    return __uint_as_float(((unsigned int)u) << 16);
}
__device__ __forceinline__ unsigned short f2bf(float f) {
    unsigned int u = __float_as_uint(f);
    return (unsigned short)((u + 0x7fffu + ((u >> 16) & 1u)) >> 16);
}

// ---------------- weight cast + pack into MFMA-fragment-linear layout -------
// Fragment = 16 n-rows x 32 k (one 16x16x32 B-operand): packed[frag][lane][8]
// = W[nt*16 + (lane&15)][kc*32 + (lane>>4)*8 + e]. GEMM loads a fragment as
// ONE coalesced 1KB global_load_dwordx4 per wave -> B never touches LDS.
__global__ __launch_bounds__(256) void cast_pack(const float* __restrict__ wqkv,
                                                 const float* __restrict__ wproj,
                                                 const float* __restrict__ wfc1,
                                                 const float* __restrict__ wfc2,
                                                 unsigned short* __restrict__ oqkv,
                                                 unsigned short* __restrict__ oproj,
                                                 unsigned short* __restrict__ ofc1,
                                                 unsigned short* __restrict__ ofc2) {
    const int t = blockIdx.x * 256 + threadIdx.x;   // 6144 blocks
    const int fi = t >> 6, l = t & 63;
    const float* src; unsigned short* dst; int KC, lf;
    if (fi < 6144)       { src = wqkv;  dst = oqkv;  KC = 32;  lf = fi; }
    else if (fi < 8192)  { src = wproj; dst = oproj; KC = 32;  lf = fi - 6144; }
    else if (fi < 16384) { src = wfc1;  dst = ofc1;  KC = 32;  lf = fi - 8192; }
    else                 { src = wfc2;  dst = ofc2;  KC = 128; lf = fi - 16384; }
    const int K = KC * 32;
    const int nt = lf / KC, kc = lf - nt * KC;
    const float* p = src + (size_t)(nt * 16 + (l & 15)) * K + kc * 32 + (l >> 4) * 8;
    f32x4 a = *(const f32x4*)p;
    f32x4 b = *(const f32x4*)(p + 4);
    u16x8 o;
    o[0] = f2bf(a.x); o[1] = f2bf(a.y); o[2] = f2bf(a.z); o[3] = f2bf(a.w);
    o[4] = f2bf(b.x); o[5] = f2bf(b.y); o[6] = f2bf(b.z); o[7] = f2bf(b.w);
    *(u16x8*)(dst + ((size_t)lf * 64 + l) * 8) = o;
}

// ---------------- LayerNorm row of 1024 -> bf16 -----------------------------
__global__ __launch_bounds__(256) void ln_bf16(const float* __restrict__ x,
                                               const float* __restrict__ w,
                                               const float* __restrict__ b,
                                               unsigned short* __restrict__ y) {
    const int m = blockIdx.x;
    const int tid = threadIdx.x;
    const float* row = x + (size_t)m * H_DIM;

    float4 v = ((const float4*)row)[tid];
    float s  = v.x + v.y + v.z + v.w;
    float ss = v.x * v.x + v.y * v.y + v.z * v.z + v.w * v.w;

    __shared__ float rs[4], rss[4], stats[2];
    const int wave = tid >> 6, lane = tid & 63;
    for (int off = 32; off; off >>= 1) {
        s  += __shfl_down(s, off);
        ss += __shfl_down(ss, off);
    }
    if (lane == 0) { rs[wave] = s; rss[wave] = ss; }
    __syncthreads();
    if (tid == 0) {
        float S = rs[0] + rs[1] + rs[2] + rs[3];
        float SS = rss[0] + rss[1] + rss[2] + rss[3];
        float mean = S * (1.0f / H_DIM);
        float var = SS * (1.0f / H_DIM) - mean * mean;
        stats[0] = mean;
        stats[1] = rsqrtf(var + LN_EPS);
    }
    __syncthreads();
    const float mean = stats[0], inv = stats[1];
    float4 wv = ((const float4*)w)[tid];
    float4 bv = ((const float4*)b)[tid];
    u16x4 o;
    o.x = f2bf((v.x - mean) * inv * wv.x + bv.x);
    o.y = f2bf((v.y - mean) * inv * wv.y + bv.y);
    o.z = f2bf((v.z - mean) * inv * wv.z + bv.z);
    o.w = f2bf((v.w - mean) * inv * wv.w + bv.w);
    ((u16x4*)(y + (size_t)m * H_DIM))[tid] = o;
}

// ---------------- bf16 MFMA GEMM v9: A via LDS, B direct-to-VGPR ------------
// r9 VERIFIED: removing B from LDS (fragment-packed weights, coalesced 1KB
// loads to VGPR, double-buffered) broke the LDS-pipe ceiling: fc2 60.5->~48,
// fc1 60->55, end-to-end -7us. Structure frozen this round.
template <int EPI, bool BF_OUT, int TN>
__device__ __forceinline__ void gemm_body(const unsigned short* __restrict__ A,
                                          const unsigned short* __restrict__ Bp,
                                          const float* __restrict__ bias,
                                          const float* __restrict__ resid,
                                          void* __restrict__ Cout,
                                          int M, int N, int K) {
    constexpr int NJ = TN / 32;                // n-frags per wave per h
    __shared__ __attribute__((aligned(16))) unsigned short As[2][128 * 64];  // 32 KB

    const int tid = threadIdx.x;
    const int wid = tid >> 6;
    const int ln  = tid & 63;
    const int quad = ln >> 4;
    const int mr   = ln & 15;
    const int wm = (wid >> 1) * 64;
    const int wn = (wid & 1) * (TN / 2);

    const int mb = M >> 7;
    const int stripe = mb >> 3;               // 4 for M=4096
    const int xcd = blockIdx.x & 7;
    const int local = blockIdx.x >> 3;
    const int m0 = (xcd * stripe + (local % stripe)) << 7;
    const int n0 = (local / stripe) * TN;

    // A staging: wave w issue i covers rows w*32+i*8+lr, lane writes 16B at
    // col lc*16; source col pre-swizzled ^(lr<<4); read applies same XOR.
    const int lr = ln >> 3, lc = ln & 7;
    const size_t Kb = (size_t)K * 2;
    const char* gA = (const char*)A + (size_t)(m0 + wid * 32 + lr) * Kb
                     + (size_t)((lc << 4) ^ (lr << 4));

    auto stage = [&](int kt, int buf) {
        const char* pa = gA + (size_t)kt * 128;
        unsigned int* la = (unsigned int*)&As[buf][0] + wid * (4 * 256);
#pragma unroll
        for (int i = 0; i < 4; i++)
            __builtin_amdgcn_global_load_lds((glb_u32*)(pa + (size_t)i * 8 * Kb),
                                             (lds_u32*)(la + i * 256), 16, 0, 0);
    };

    // B fragments from packed weights: frag idx = (n/16)*KC + (k/32).
    const int KC = K >> 5;
    const unsigned short* gBp = Bp + ((size_t)((n0 + wn) >> 4) * KC * 64 + ln) * 8;
    auto loadB = [&](int kt, u16x8 (&bb)[NJ][2]) {
#pragma unroll
        for (int j = 0; j < NJ; j++)
#pragma unroll
            for (int h = 0; h < 2; h++)
                bb[j][h] = *(const u16x8*)(gBp
                              + ((size_t)j * KC + (kt * 2 + h)) * 64 * 8);
    };

    const f32x4 zero = {0.f, 0.f, 0.f, 0.f};
    f32x4 acc[4][NJ];
#pragma unroll
    for (int i = 0; i < 4; i++)
#pragma unroll
        for (int j = 0; j < NJ; j++) acc[i][j] = zero;

    const int swz = (mr & 7) << 3;            // read-side XOR (shorts)
    auto compute = [&](const unsigned short* As_, u16x8 (&bc)[NJ][2]) {
#pragma unroll
        for (int h = 0; h < 2; h++) {
            short8 af[4];
#pragma unroll
            for (int i = 0; i < 4; i++)
                af[i] = *(const short8*)(As_ + (wm + i * 16 + mr) * 64
                                             + ((h * 32 + quad * 8) ^ swz));
#pragma unroll
            for (int i = 0; i < 4; i++)
#pragma unroll
                for (int j = 0; j < NJ; j++)
                    acc[i][j] = __builtin_amdgcn_mfma_f32_16x16x32_bf16(
                        (short8)bc[j][h], af[i], acc[i][j], 0, 0, 0);
        }
    };

    u16x8 bA[NJ][2], bB[NJ][2];               // static names (rule #20)
    const int nt = K >> 6;                    // 16 or 64: always even
    stage(0, 0);
    stage(1, 1);
    loadB(0, bA);

    for (int kt = 0; kt < nt; kt += 2) {
        // ---- even step: tile kt in As[0], B in bA ----
        if (kt + 1 < nt) {
            if (TN == 128) ASM_VMCNT(12); else ASM_VMCNT(8);
        } else {
            if (TN == 128) ASM_VMCNT(8);  else ASM_VMCNT(4);
        }
        __builtin_amdgcn_s_barrier();
        if (kt + 1 < nt) loadB(kt + 1, bB);
        __builtin_amdgcn_sched_barrier(0);
        compute(&As[0][0], bA);
        __builtin_amdgcn_sched_barrier(0);
        __builtin_amdgcn_s_barrier();
        if (kt + 2 < nt) stage(kt + 2, 0);
        // ---- odd step: tile kt+1 in As[1], B in bB ----
        if (kt + 2 < nt) {
            if (TN == 128) ASM_VMCNT(12); else ASM_VMCNT(8);
        } else {
            if (TN == 128) ASM_VMCNT(8);  else ASM_VMCNT(4);
        }
        __builtin_amdgcn_s_barrier();
        if (kt + 2 < nt) loadB(kt + 2, bA);
        __builtin_amdgcn_sched_barrier(0);
        compute(&As[1][0], bB);
        __builtin_amdgcn_sched_barrier(0);
        __builtin_amdgcn_s_barrier();
        if (kt + 3 < nt) stage(kt + 3, 1);
    }

    // epilogue
    f32x4 bias4[NJ];
#pragma unroll
    for (int j = 0; j < NJ; j++)
        bias4[j] = *(const f32x4*)(bias + n0 + wn + j * 16 + quad * 4);

#pragma unroll
    for (int i = 0; i < 4; i++) {
        const int m = m0 + wm + i * 16 + mr;
#pragma unroll
        for (int j = 0; j < NJ; j++) {
            const int nb = n0 + wn + j * 16 + quad * 4;
            f32x4 v = acc[i][j] + bias4[j];
            if (EPI == 1) v += *(const f32x4*)(resid + (size_t)m * N + nb);
            if (EPI == 2) {
#pragma unroll
                for (int r = 0; r < 4; r++) {
                    // gelu(tanh) via exp2: x*e/(e+1) written NaN-safe as x - x/(e+1)
                    const float t = v[r];
                    const float u = t + 0.044715f * t * t * t;
                    const float e = exp2f(2.3022112f * u);   // 2*log2(e)*0.79788456
                    v[r] = t - t / (e + 1.0f);
                }
            }
            if (BF_OUT) {
                u16x4 pk;
                pk.x = f2bf(v.x); pk.y = f2bf(v.y); pk.z = f2bf(v.z); pk.w = f2bf(v.w);
                *(u16x4*)((unsigned short*)Cout + (size_t)m * N + nb) = pk;
            } else {
                *(f32x4*)((float*)Cout + (size_t)m * N + nb) = v;
            }
        }
    }
}

// ---- named instantiations: one kernel symbol per op for rocprof attribution
__global__ __launch_bounds__(256) void gemm_qkv(const unsigned short* __restrict__ A,
                                                const unsigned short* __restrict__ B,
                                                const float* __restrict__ bias,
                                                void* __restrict__ Cout,
                                                int M, int N, int K) {
    gemm_body<0, true, 128>(A, B, bias, nullptr, Cout, M, N, K);
}
__global__ __launch_bounds__(256) void gemm_proj(const unsigned short* __restrict__ A,
                                                 const unsigned short* __restrict__ B,
                                                 const float* __restrict__ bias,
                                                 const float* __restrict__ resid,
                                                 void* __restrict__ Cout,
                                                 int M, int N, int K) {
    gemm_body<1, false, 64>(A, B, bias, resid, Cout, M, N, K);
}
__global__ __launch_bounds__(256) void gemm_fc1(const unsigned short* __restrict__ A,
                                                const unsigned short* __restrict__ B,
                                                const float* __restrict__ bias,
                                                void* __restrict__ Cout,
                                                int M, int N, int K) {
    gemm_body<2, true, 128>(A, B, bias, nullptr, Cout, M, N, K);
}
__global__ __launch_bounds__(256) void gemm_fc2(const unsigned short* __restrict__ A,
                                                const unsigned short* __restrict__ B,
                                                const float* __restrict__ bias,
                                                const float* __restrict__ resid,
                                                void* __restrict__ Cout,
                                                int M, int N, int K) {
    gemm_body<1, false, 64>(A, B, bias, resid, Cout, M, N, K);
}

// ---------------- MFMA flash attention v4 -----------------------------------
// r9 diagnosis: attn was grid-starved (512 blocks = 2 blocks/CU = 25% wave
// cap; VALUBusy 47% with MfmaUtil 12% -> VALU-bound with no TLP to overlap).
// v4: one q-tile per block -> grid 1024 = 4 blocks/CU. Pairing removed; ids
// ordered so big tiles (qt=31) launch first and short tiles backfill the
// tail. XCD-locality kept: id&7 = xcd, each (b,nh) stays on one XCD
// (K+V/head = 512 KB; 4 heads/XCD = 2 MB < 4 MB L2). Inner loop unchanged.
__global__ __launch_bounds__(256) void attn_mfma(const unsigned short* __restrict__ qkv,
                                                 unsigned short* __restrict__ out) {
    __shared__ __attribute__((aligned(16))) unsigned short Ks[64 * KSTR];
    __shared__ __attribute__((aligned(16))) unsigned short Vs[64 * KSTR];
    __shared__ __attribute__((aligned(16))) unsigned short Ps[64 * KSTR];

    const int tid = threadIdx.x;
    const int wid = tid >> 6;
    const int ln  = tid & 63;
    const int quad = ln >> 4;
    const int mr   = ln & 15;

    const int id = blockIdx.x;                 // 0..1023
    const int local = id >> 3;                 // 0..127
    const int bh = (id & 7) * 4 + (local >> 5);
    const int qt = 31 - (local & 31);          // big tiles first
    const int b  = bh >> 4;
    const int nh = bh & 15;
    const size_t chan = (size_t)nh * 192;
    const int qb = qt * 64;

    const int ksr = tid >> 2, ksc = tid & 3;
    const int vt0 = (tid & 31) * 2, vd0 = (tid >> 5) * 8;

    u16x8 kp0, kp1, vp0, vp1;   // prefetch registers

    short8 qf0, qf1;
    {
        const int qrow = qb + wid * 16 + mr;
        const unsigned short* gq = qkv + ((size_t)(qrow * 2 + b)) * 3072 + chan + quad * 8;
        qf0 = *(const short8*)gq;
        qf1 = *(const short8*)(gq + 32);
    }

    const f32x4 zero = {0.f, 0.f, 0.f, 0.f};
    f32x4 o[4];
    float ps = 0.f;
#pragma unroll
    for (int d = 0; d < 4; d++) o[d] = zero;

    {
        const unsigned short* gk = qkv + ((size_t)(ksr * 2 + b)) * 3072 + chan + 64 + ksc * 16;
        kp0 = *(const u16x8*)gk;
        kp1 = *(const u16x8*)(gk + 8);
        const unsigned short* gv = qkv + ((size_t)(vt0 * 2 + b)) * 3072 + chan + 128 + vd0;
        vp0 = *(const u16x8*)gv;
        vp1 = *(const u16x8*)(gv + 6144);
    }

    for (int kt = 0; kt <= qt; kt++) {
        __syncthreads();
        *(u16x8*)(Ks + ksr * KSTR + ksc * 16) = kp0;
        *(u16x8*)(Ks + ksr * KSTR + ksc * 16 + 8) = kp1;
#pragma unroll
        for (int j = 0; j < 8; j++) {
            u16x2 pr; pr.x = vp0[j]; pr.y = vp1[j];
            *(u16x2*)(Vs + (vd0 + j) * KSTR + vt0) = pr;
        }
        if (kt < qt) {
            const int nb = (kt + 1) * 64;
            const unsigned short* gk =
                qkv + ((size_t)((nb + ksr) * 2 + b)) * 3072 + chan + 64 + ksc * 16;
            kp0 = *(const u16x8*)gk;
            kp1 = *(const u16x8*)(gk + 8);
            const unsigned short* gv =
                qkv + ((size_t)((nb + vt0) * 2 + b)) * 3072 + chan + 128 + vd0;
            vp0 = *(const u16x8*)gv;
            vp1 = *(const u16x8*)(gv + 6144);
        }
        __syncthreads();

        // ---- S^T = K Q^T: lane owns q=mr, t = n*16 + quad*4 + r ----
        f32x4 sacc[4];
#pragma unroll
        for (int n = 0; n < 4; n++) {
            sacc[n] = zero;
            const unsigned short* kb = Ks + (n * 16 + mr) * KSTR + quad * 8;
            short8 kfr0 = *(const short8*)kb;
            short8 kfr1 = *(const short8*)(kb + 32);
            sacc[n] = __builtin_amdgcn_mfma_f32_16x16x32_bf16(kfr0, qf0, sacc[n], 0, 0, 0);
            sacc[n] = __builtin_amdgcn_mfma_f32_16x16x32_bf16(kfr1, qf1, sacc[n], 0, 0, 0);
        }
        if (kt == qt) {
#pragma unroll
            for (int n = 0; n < 4; n++)
#pragma unroll
                for (int r = 0; r < 4; r++)
                    if (n * 16 + quad * 4 + r > wid * 16 + mr) sacc[n][r] = -3.0e38f;
        }

        // ---- max-free softmax: p = 2^(s*SCL), clamped; fp32 row-partials ----
        unsigned short* prow = Ps + (wid * 16 + mr) * KSTR + quad * 4;
#pragma unroll
        for (int n = 0; n < 4; n++) {
            u16x4 pk;
#pragma unroll
            for (int r = 0; r < 4; r++) {
                const float p = exp2f(fminf(sacc[n][r] * SCL, 80.f));
                ps += p;
                pk[r] = (unsigned short)(__float_as_uint(p) >> 16);
            }
            *(u16x4*)(prow + n * 16) = pk;
        }

        // ---- O^T += V^T P^T: lane owns q=mr, d = dblk*16 + quad*4 + r ----
        {
            const unsigned short* pb = Ps + (wid * 16 + mr) * KSTR + quad * 8;
            short8 pa0 = *(const short8*)pb;
            short8 pa1 = *(const short8*)(pb + 32);
#pragma unroll
            for (int d = 0; d < 4; d++) {
                const unsigned short* vb = Vs + (d * 16 + mr) * KSTR + quad * 8;
                short8 vf0 = *(const short8*)vb;
                short8 vf1 = *(const short8*)(vb + 32);
                o[d] = __builtin_amdgcn_mfma_f32_16x16x32_bf16(vf0, pa0, o[d], 0, 0, 0);
                o[d] = __builtin_amdgcn_mfma_f32_16x16x32_bf16(vf1, pa1, o[d], 0, 0, 0);
            }
        }
    }

    // ---- epilogue: l[q=mr] via 2 shfl_xor; vectorized O store ----
    ps += __shfl_xor(ps, 16);
    ps += __shfl_xor(ps, 32);
    const float inv = 1.0f / ps;
    const int qrow = qb + wid * 16 + mr;
    unsigned short* po = out + ((size_t)(qrow * 2 + b)) * H_DIM + nh * HDIM;
#pragma unroll
    for (int d = 0; d < 4; d++) {
        u16x4 pk;
#pragma unroll
        for (int r = 0; r < 4; r++) pk[r] = f2bf(o[d][r] * inv);
        *(u16x4*)(po + d * 16 + quad * 4) = pk;
    }
}

extern "C" void kernel_launch(void* const* d_in, const int* in_sizes, int n_in,
                              void* d_out, int out_size, void* d_ws, size_t ws_size,
                              hipStream_t stream) {
    const float* x      = (const float*)d_in[0];
    const float* ln1_w  = (const float*)d_in[1];
    const float* ln1_b  = (const float*)d_in[2];
    const float* w_qkv  = (const float*)d_in[3];
    const float* b_qkv  = (const float*)d_in[4];
    const float* w_proj = (const float*)d_in[5];
    const float* b_proj = (const float*)d_in[6];
    const float* ln2_w  = (const float*)d_in[7];
    const float* ln2_b  = (const float*)d_in[8];
    const float* w_fc1  = (const float*)d_in[9];
    const float* b_fc1  = (const float*)d_in[10];
    const float* w_fc2  = (const float*)d_in[11];
    const float* b_fc2  = (const float*)d_in[12];
    float* out = (float*)d_out;

    char* ws = (char*)d_ws;
    unsigned short* wqkv_bf  = (unsigned short*)(ws);                        // 6 MB (packed)
    unsigned short* wproj_bf = (unsigned short*)(ws + ((size_t)6 << 20));    // 2 MB (packed)
    unsigned short* wfc1_bf  = (unsigned short*)(ws + ((size_t)8 << 20));    // 8 MB (packed)
    unsigned short* wfc2_bf  = (unsigned short*)(ws + ((size_t)16 << 20));   // 8 MB (packed)
    unsigned short* ln_buf   = (unsigned short*)(ws + ((size_t)24 << 20));   // 8 MB
    unsigned short* qkv_bf   = (unsigned short*)(ws + ((size_t)32 << 20));   // 24 MB
    unsigned short* attn_bf  = (unsigned short*)(ws + ((size_t)56 << 20));   // 8 MB
    unsigned short* fc1_bf   = (unsigned short*)(ws + ((size_t)32 << 20));   // 32 MB (qkv/attn dead)

    cast_pack<<<6144, 256, 0, stream>>>(w_qkv, w_proj, w_fc1, w_fc2,
                                        wqkv_bf, wproj_bf, wfc1_bf, wfc2_bf);

    // 1) LN1 -> bf16
    ln_bf16<<<M_ROWS, 256, 0, stream>>>(x, ln1_w, ln1_b, ln_buf);
    // 2) qkv = ln1 @ w_qkv^T + b_qkv   [4096,3072] bf16   (768 blocks)
    gemm_qkv<<<768, 256, 0, stream>>>(ln_buf, wqkv_bf, b_qkv, qkv_bf,
                                      M_ROWS, 3072, 1024);
    // 3) MFMA flash attention -> bf16 [4096,1024]   (1024 blocks, 4/CU)
    attn_mfma<<<1024, 256, 0, stream>>>(qkv_bf, attn_bf);
    // 4) x1 = x + attn @ w_proj^T + b_proj  -> d_out (fp32)   (512 blocks)
    gemm_proj<<<512, 256, 0, stream>>>(attn_bf, wproj_bf, b_proj, x, out,
                                       M_ROWS, 1024, 1024);
    // 5) LN2 -> bf16
    ln_bf16<<<M_ROWS, 256, 0, stream>>>(out, ln2_w, ln2_b, ln_buf);
    // 6) fc1 + gelu -> bf16 [4096,4096]   (1024 blocks)
    gemm_fc1<<<1024, 256, 0, stream>>>(ln_buf, wfc1_bf, b_fc1, fc1_bf,
                                       M_ROWS, 4096, 1024);
    // 7) out = x1 + fc1 @ w_fc2^T + b_fc2 (in-place residual)   (512 blocks)
    gemm_fc2<<<512, 256, 0, stream>>>(fc1_bf, wfc2_bf, b_fc2, out, out,
                                      M_ROWS, 1024, 4096);
}

// Round 11
// 330.180 us; speedup vs baseline: 1.0282x; 1.0282x over previous
//
#include <hip/hip_runtime.h>
#include <math.h>

#define S_LEN 2048
#define B_SZ 2
#define NHEAD 16
#define HDIM 64
#define H_DIM 1024
#define M_ROWS (S_LEN * B_SZ)   // 4096
#define LN_EPS 1e-5f
#define KSTR 72                  // attn LDS row stride (shorts)
#define SCL 0.18033688011112042f // 0.125 * log2(e)

typedef __attribute__((ext_vector_type(4))) float f32x4;
typedef __attribute__((ext_vector_type(8))) short short8;
typedef __attribute__((ext_vector_type(8))) unsigned short u16x8;
typedef __attribute__((ext_vector_type(4))) unsigned short u16x4;
typedef __attribute__((ext_vector_type(2))) unsigned short u16x2;

typedef __attribute__((address_space(3))) unsigned int lds_u32;
typedef const __attribute__((address_space(1))) unsigned int glb_u32;

#define ASM_VMCNT(N) asm volatile("s_waitcnt vmcnt(" #N ")" ::: "memory")

__device__ __forceinline__ float bf2f(unsigned short u) {
    return __uint_as_float(((unsigned int)u) << 16);
}
__device__ __forceinline__ unsigned short f2bf(float f) {
    unsigned int u = __float_as_uint(f);
    return (unsigned short)((u + 0x7fffu + ((u >> 16) & 1u)) >> 16);
}

// ---------------- weight cast + pack into MFMA-fragment-linear layout -------
// Fragment = 16 n-rows x 32 k (one 16x16x32 B-operand): packed[frag][lane][8]
// = W[nt*16 + (lane&15)][kc*32 + (lane>>4)*8 + e]. GEMM loads a fragment as
// ONE coalesced 1KB global_load_dwordx4 per wave -> B never touches LDS.
__global__ __launch_bounds__(256) void cast_pack(const float* __restrict__ wqkv,
                                                 const float* __restrict__ wproj,
                                                 const float* __restrict__ wfc1,
                                                 const float* __restrict__ wfc2,
                                                 unsigned short* __restrict__ oqkv,
                                                 unsigned short* __restrict__ oproj,
                                                 unsigned short* __restrict__ ofc1,
                                                 unsigned short* __restrict__ ofc2) {
    const int t = blockIdx.x * 256 + threadIdx.x;   // 6144 blocks
    const int fi = t >> 6, l = t & 63;
    const float* src; unsigned short* dst; int KC, lf;
    if (fi < 6144)       { src = wqkv;  dst = oqkv;  KC = 32;  lf = fi; }
    else if (fi < 8192)  { src = wproj; dst = oproj; KC = 32;  lf = fi - 6144; }
    else if (fi < 16384) { src = wfc1;  dst = ofc1;  KC = 32;  lf = fi - 8192; }
    else                 { src = wfc2;  dst = ofc2;  KC = 128; lf = fi - 16384; }
    const int K = KC * 32;
    const int nt = lf / KC, kc = lf - nt * KC;
    const float* p = src + (size_t)(nt * 16 + (l & 15)) * K + kc * 32 + (l >> 4) * 8;
    f32x4 a = *(const f32x4*)p;
    f32x4 b = *(const f32x4*)(p + 4);
    u16x8 o;
    o[0] = f2bf(a.x); o[1] = f2bf(a.y); o[2] = f2bf(a.z); o[3] = f2bf(a.w);
    o[4] = f2bf(b.x); o[5] = f2bf(b.y); o[6] = f2bf(b.z); o[7] = f2bf(b.w);
    *(u16x8*)(dst + ((size_t)lf * 64 + l) * 8) = o;
}

// ---------------- LayerNorm row of 1024 -> bf16 -----------------------------
__global__ __launch_bounds__(256) void ln_bf16(const float* __restrict__ x,
                                               const float* __restrict__ w,
                                               const float* __restrict__ b,
                                               unsigned short* __restrict__ y) {
    const int m = blockIdx.x;
    const int tid = threadIdx.x;
    const float* row = x + (size_t)m * H_DIM;

    float4 v = ((const float4*)row)[tid];
    float s  = v.x + v.y + v.z + v.w;
    float ss = v.x * v.x + v.y * v.y + v.z * v.z + v.w * v.w;

    __shared__ float rs[4], rss[4], stats[2];
    const int wave = tid >> 6, lane = tid & 63;
    for (int off = 32; off; off >>= 1) {
        s  += __shfl_down(s, off);
        ss += __shfl_down(ss, off);
    }
    if (lane == 0) { rs[wave] = s; rss[wave] = ss; }
    __syncthreads();
    if (tid == 0) {
        float S = rs[0] + rs[1] + rs[2] + rs[3];
        float SS = rss[0] + rss[1] + rss[2] + rss[3];
        float mean = S * (1.0f / H_DIM);
        float var = SS * (1.0f / H_DIM) - mean * mean;
        stats[0] = mean;
        stats[1] = rsqrtf(var + LN_EPS);
    }
    __syncthreads();
    const float mean = stats[0], inv = stats[1];
    float4 wv = ((const float4*)w)[tid];
    float4 bv = ((const float4*)b)[tid];
    u16x4 o;
    o.x = f2bf((v.x - mean) * inv * wv.x + bv.x);
    o.y = f2bf((v.y - mean) * inv * wv.y + bv.y);
    o.z = f2bf((v.z - mean) * inv * wv.z + bv.z);
    o.w = f2bf((v.w - mean) * inv * wv.w + bv.w);
    ((u16x4*)(y + (size_t)m * H_DIM))[tid] = o;
}

// ---------------- bf16 MFMA GEMM v10: B-in-reg + strength-reduced pointers --
// r9 VERIFIED: B direct-to-VGPR from fragment-packed weights broke the LDS
// ceiling. r10 lesson: OccupancyPercent is a broken derived counter on
// gfx950 (constant ~19% across all kernels/configs) -- ignore it. fc1 is
// VALU+latency bound; v10 strength-reduces all per-K-step address math to
// pointer increments (pB += 1024 shorts, pA += 128 B per tile; j/h offsets
// hoisted loop-invariant). vmcnt ledger identical to r9 (same op counts).
template <int EPI, bool BF_OUT, int TN>
__device__ __forceinline__ void gemm_body(const unsigned short* __restrict__ A,
                                          const unsigned short* __restrict__ Bp,
                                          const float* __restrict__ bias,
                                          const float* __restrict__ resid,
                                          void* __restrict__ Cout,
                                          int M, int N, int K) {
    constexpr int NJ = TN / 32;                // n-frags per wave per h
    __shared__ __attribute__((aligned(16))) unsigned short As[2][128 * 64];  // 32 KB

    const int tid = threadIdx.x;
    const int wid = tid >> 6;
    const int ln  = tid & 63;
    const int quad = ln >> 4;
    const int mr   = ln & 15;
    const int wm = (wid >> 1) * 64;
    const int wn = (wid & 1) * (TN / 2);

    const int mb = M >> 7;
    const int stripe = mb >> 3;               // 4 for M=4096
    const int xcd = blockIdx.x & 7;
    const int local = blockIdx.x >> 3;
    const int m0 = (xcd * stripe + (local % stripe)) << 7;
    const int n0 = (local / stripe) * TN;

    // A staging: wave w issue i covers rows w*32+i*8+lr, lane writes 16B at
    // col lc*16; source col pre-swizzled ^(lr<<4); read applies same XOR.
    const int lr = ln >> 3, lc = ln & 7;
    const size_t Kb = (size_t)K * 2;
    const char* gA = (const char*)A + (size_t)(m0 + wid * 32 + lr) * Kb
                     + (size_t)((lc << 4) ^ (lr << 4));
    unsigned int* la0 = (unsigned int*)&As[0][0] + wid * (4 * 256);
    unsigned int* la1 = (unsigned int*)&As[1][0] + wid * (4 * 256);

    auto stage = [&](const char* pa, unsigned int* la) {
#pragma unroll
        for (int i = 0; i < 4; i++)
            __builtin_amdgcn_global_load_lds((glb_u32*)(pa + (size_t)i * 8 * Kb),
                                             (lds_u32*)(la + i * 256), 16, 0, 0);
    };

    // B fragments from packed weights: frag idx = (n/16)*KC + (k/32); one
    // tile (BK=64) = 2 consecutive fragments = 1024 shorts. Pointer-stepped.
    const int KC = K >> 5;
    const size_t jstr = (size_t)KC * 512;     // shorts between j-fragments
    const unsigned short* gBp = Bp + ((size_t)((n0 + wn) >> 4) * KC * 64 + ln) * 8;
    auto loadB = [&](const unsigned short* p, u16x8 (&bb)[NJ][2]) {
#pragma unroll
        for (int j = 0; j < NJ; j++)
#pragma unroll
            for (int h = 0; h < 2; h++)
                bb[j][h] = *(const u16x8*)(p + (size_t)j * jstr + h * 512);
    };

    const f32x4 zero = {0.f, 0.f, 0.f, 0.f};
    f32x4 acc[4][NJ];
#pragma unroll
    for (int i = 0; i < 4; i++)
#pragma unroll
        for (int j = 0; j < NJ; j++) acc[i][j] = zero;

    const int swz = (mr & 7) << 3;            // read-side XOR (shorts)
    auto compute = [&](const unsigned short* As_, u16x8 (&bc)[NJ][2]) {
#pragma unroll
        for (int h = 0; h < 2; h++) {
            short8 af[4];
#pragma unroll
            for (int i = 0; i < 4; i++)
                af[i] = *(const short8*)(As_ + (wm + i * 16 + mr) * 64
                                             + ((h * 32 + quad * 8) ^ swz));
#pragma unroll
            for (int i = 0; i < 4; i++)
#pragma unroll
                for (int j = 0; j < NJ; j++)
                    acc[i][j] = __builtin_amdgcn_mfma_f32_16x16x32_bf16(
                        (short8)bc[j][h], af[i], acc[i][j], 0, 0, 0);
        }
    };

    u16x8 bA[NJ][2], bB[NJ][2];               // static names (rule #20)
    const int nt = K >> 6;                    // 16 or 64: always even
    stage(gA, la0);
    stage(gA + 128, la1);
    loadB(gBp, bA);
    const char* pAn = gA + 256;               // next A tile to stage (kt=2)
    const unsigned short* pBn = gBp + 1024;   // next B tile to load (kt=1)

    for (int kt = 0; kt < nt; kt += 2) {
        // ---- even step: tile kt in As[0], B in bA ----
        if (kt + 1 < nt) {
            if (TN == 128) ASM_VMCNT(12); else ASM_VMCNT(8);
        } else {
            if (TN == 128) ASM_VMCNT(8);  else ASM_VMCNT(4);
        }
        __builtin_amdgcn_s_barrier();
        if (kt + 1 < nt) { loadB(pBn, bB); pBn += 1024; }
        __builtin_amdgcn_sched_barrier(0);
        compute(&As[0][0], bA);
        __builtin_amdgcn_sched_barrier(0);
        __builtin_amdgcn_s_barrier();
        if (kt + 2 < nt) { stage(pAn, la0); pAn += 128; }
        // ---- odd step: tile kt+1 in As[1], B in bB ----
        if (kt + 2 < nt) {
            if (TN == 128) ASM_VMCNT(12); else ASM_VMCNT(8);
        } else {
            if (TN == 128) ASM_VMCNT(8);  else ASM_VMCNT(4);
        }
        __builtin_amdgcn_s_barrier();
        if (kt + 2 < nt) { loadB(pBn, bA); pBn += 1024; }
        __builtin_amdgcn_sched_barrier(0);
        compute(&As[1][0], bB);
        __builtin_amdgcn_sched_barrier(0);
        __builtin_amdgcn_s_barrier();
        if (kt + 3 < nt) { stage(pAn, la1); pAn += 128; }
    }

    // epilogue
    f32x4 bias4[NJ];
#pragma unroll
    for (int j = 0; j < NJ; j++)
        bias4[j] = *(const f32x4*)(bias + n0 + wn + j * 16 + quad * 4);

#pragma unroll
    for (int i = 0; i < 4; i++) {
        const int m = m0 + wm + i * 16 + mr;
#pragma unroll
        for (int j = 0; j < NJ; j++) {
            const int nb = n0 + wn + j * 16 + quad * 4;
            f32x4 v = acc[i][j] + bias4[j];
            if (EPI == 1) v += *(const f32x4*)(resid + (size_t)m * N + nb);
            if (EPI == 2) {
#pragma unroll
                for (int r = 0; r < 4; r++) {
                    // gelu(tanh) via exp2: x*e/(e+1) written NaN-safe as x - x/(e+1)
                    const float t = v[r];
                    const float u = t + 0.044715f * t * t * t;
                    const float e = exp2f(2.3022112f * u);   // 2*log2(e)*0.79788456
                    v[r] = t - t / (e + 1.0f);
                }
            }
            if (BF_OUT) {
                u16x4 pk;
                pk.x = f2bf(v.x); pk.y = f2bf(v.y); pk.z = f2bf(v.z); pk.w = f2bf(v.w);
                *(u16x4*)((unsigned short*)Cout + (size_t)m * N + nb) = pk;
            } else {
                *(f32x4*)((float*)Cout + (size_t)m * N + nb) = v;
            }
        }
    }
}

// ---- named instantiations: one kernel symbol per op for rocprof attribution
__global__ __launch_bounds__(256) void gemm_qkv(const unsigned short* __restrict__ A,
                                                const unsigned short* __restrict__ B,
                                                const float* __restrict__ bias,
                                                void* __restrict__ Cout,
                                                int M, int N, int K) {
    gemm_body<0, true, 128>(A, B, bias, nullptr, Cout, M, N, K);
}
__global__ __launch_bounds__(256) void gemm_proj(const unsigned short* __restrict__ A,
                                                 const unsigned short* __restrict__ B,
                                                 const float* __restrict__ bias,
                                                 const float* __restrict__ resid,
                                                 void* __restrict__ Cout,
                                                 int M, int N, int K) {
    gemm_body<1, false, 64>(A, B, bias, resid, Cout, M, N, K);
}
__global__ __launch_bounds__(256) void gemm_fc1(const unsigned short* __restrict__ A,
                                                const unsigned short* __restrict__ B,
                                                const float* __restrict__ bias,
                                                void* __restrict__ Cout,
                                                int M, int N, int K) {
    gemm_body<2, true, 128>(A, B, bias, nullptr, Cout, M, N, K);
}
__global__ __launch_bounds__(256) void gemm_fc2(const unsigned short* __restrict__ A,
                                                const unsigned short* __restrict__ B,
                                                const float* __restrict__ bias,
                                                const float* __restrict__ resid,
                                                void* __restrict__ Cout,
                                                int M, int N, int K) {
    gemm_body<1, false, 64>(A, B, bias, resid, Cout, M, N, K);
}

// ---------------- MFMA flash attention v3 (r9 paired version, best: 55us) ---
// r10 falsified the grid-split: 1024 1-tile blocks = 63us (>55) with
// occupancy counter unmoved (counter unreliable on gfx950). Paired q-tiles
// (qt=pa and 31-pa) per block restore per-block load balance + halve
// per-block fixed overhead. XCD-local K/V (id&7 = xcd).
__global__ __launch_bounds__(256) void attn_mfma(const unsigned short* __restrict__ qkv,
                                                 unsigned short* __restrict__ out) {
    __shared__ __attribute__((aligned(16))) unsigned short Ks[64 * KSTR];
    __shared__ __attribute__((aligned(16))) unsigned short Vs[64 * KSTR];
    __shared__ __attribute__((aligned(16))) unsigned short Ps[64 * KSTR];

    const int tid = threadIdx.x;
    const int wid = tid >> 6;
    const int ln  = tid & 63;
    const int quad = ln >> 4;
    const int mr   = ln & 15;

    const int id = blockIdx.x;                 // 0..511
    const int local = id >> 3;                 // 0..63
    const int bh = (id & 7) * 4 + (local >> 4);
    const int pa = local & 15;
    const int b  = bh >> 4;
    const int nh = bh & 15;
    const size_t chan = (size_t)nh * 192;

    const int ksr = tid >> 2, ksc = tid & 3;
    const int vt0 = (tid & 31) * 2, vd0 = (tid >> 5) * 8;

    u16x8 kp0, kp1, vp0, vp1;   // prefetch registers

#pragma unroll
    for (int half = 0; half < 2; half++) {
        const int qt = half ? (31 - pa) : pa;
        const int qb = qt * 64;

        short8 qf0, qf1;
        {
            const int qrow = qb + wid * 16 + mr;
            const unsigned short* gq = qkv + ((size_t)(qrow * 2 + b)) * 3072 + chan + quad * 8;
            qf0 = *(const short8*)gq;
            qf1 = *(const short8*)(gq + 32);
        }

        const f32x4 zero = {0.f, 0.f, 0.f, 0.f};
        f32x4 o[4];
        float ps = 0.f;
#pragma unroll
        for (int d = 0; d < 4; d++) o[d] = zero;

        {
            const unsigned short* gk = qkv + ((size_t)(ksr * 2 + b)) * 3072 + chan + 64 + ksc * 16;
            kp0 = *(const u16x8*)gk;
            kp1 = *(const u16x8*)(gk + 8);
            const unsigned short* gv = qkv + ((size_t)(vt0 * 2 + b)) * 3072 + chan + 128 + vd0;
            vp0 = *(const u16x8*)gv;
            vp1 = *(const u16x8*)(gv + 6144);
        }

        for (int kt = 0; kt <= qt; kt++) {
            __syncthreads();
            *(u16x8*)(Ks + ksr * KSTR + ksc * 16) = kp0;
            *(u16x8*)(Ks + ksr * KSTR + ksc * 16 + 8) = kp1;
#pragma unroll
            for (int j = 0; j < 8; j++) {
                u16x2 pr; pr.x = vp0[j]; pr.y = vp1[j];
                *(u16x2*)(Vs + (vd0 + j) * KSTR + vt0) = pr;
            }
            if (kt < qt) {
                const int nb = (kt + 1) * 64;
                const unsigned short* gk =
                    qkv + ((size_t)((nb + ksr) * 2 + b)) * 3072 + chan + 64 + ksc * 16;
                kp0 = *(const u16x8*)gk;
                kp1 = *(const u16x8*)(gk + 8);
                const unsigned short* gv =
                    qkv + ((size_t)((nb + vt0) * 2 + b)) * 3072 + chan + 128 + vd0;
                vp0 = *(const u16x8*)gv;
                vp1 = *(const u16x8*)(gv + 6144);
            }
            __syncthreads();

            // ---- S^T = K Q^T: lane owns q=mr, t = n*16 + quad*4 + r ----
            f32x4 sacc[4];
#pragma unroll
            for (int n = 0; n < 4; n++) {
                sacc[n] = zero;
                const unsigned short* kb = Ks + (n * 16 + mr) * KSTR + quad * 8;
                short8 kfr0 = *(const short8*)kb;
                short8 kfr1 = *(const short8*)(kb + 32);
                sacc[n] = __builtin_amdgcn_mfma_f32_16x16x32_bf16(kfr0, qf0, sacc[n], 0, 0, 0);
                sacc[n] = __builtin_amdgcn_mfma_f32_16x16x32_bf16(kfr1, qf1, sacc[n], 0, 0, 0);
            }
            if (kt == qt) {
#pragma unroll
                for (int n = 0; n < 4; n++)
#pragma unroll
                    for (int r = 0; r < 4; r++)
                        if (n * 16 + quad * 4 + r > wid * 16 + mr) sacc[n][r] = -3.0e38f;
            }

            // ---- max-free softmax: p = 2^(s*SCL), clamped; fp32 row-partials ----
            unsigned short* prow = Ps + (wid * 16 + mr) * KSTR + quad * 4;
#pragma unroll
            for (int n = 0; n < 4; n++) {
                u16x4 pk;
#pragma unroll
                for (int r = 0; r < 4; r++) {
                    const float p = exp2f(fminf(sacc[n][r] * SCL, 80.f));
                    ps += p;
                    pk[r] = (unsigned short)(__float_as_uint(p) >> 16);
                }
                *(u16x4*)(prow + n * 16) = pk;
            }

            // ---- O^T += V^T P^T: lane owns q=mr, d = dblk*16 + quad*4 + r ----
            {
                const unsigned short* pb = Ps + (wid * 16 + mr) * KSTR + quad * 8;
                short8 pa0 = *(const short8*)pb;
                short8 pa1 = *(const short8*)(pb + 32);
#pragma unroll
                for (int d = 0; d < 4; d++) {
                    const unsigned short* vb = Vs + (d * 16 + mr) * KSTR + quad * 8;
                    short8 vf0 = *(const short8*)vb;
                    short8 vf1 = *(const short8*)(vb + 32);
                    o[d] = __builtin_amdgcn_mfma_f32_16x16x32_bf16(vf0, pa0, o[d], 0, 0, 0);
                    o[d] = __builtin_amdgcn_mfma_f32_16x16x32_bf16(vf1, pa1, o[d], 0, 0, 0);
                }
            }
        }

        // ---- epilogue: l[q=mr] via 2 shfl_xor; vectorized O store ----
        ps += __shfl_xor(ps, 16);
        ps += __shfl_xor(ps, 32);
        const float inv = 1.0f / ps;
        const int qrow = qb + wid * 16 + mr;
        unsigned short* po = out + ((size_t)(qrow * 2 + b)) * H_DIM + nh * HDIM;
#pragma unroll
        for (int d = 0; d < 4; d++) {
            u16x4 pk;
#pragma unroll
            for (int r = 0; r < 4; r++) pk[r] = f2bf(o[d][r] * inv);
            *(u16x4*)(po + d * 16 + quad * 4) = pk;
        }
    }
}

extern "C" void kernel_launch(void* const* d_in, const int* in_sizes, int n_in,
                              void* d_out, int out_size, void* d_ws, size_t ws_size,
                              hipStream_t stream) {
    const float* x      = (const float*)d_in[0];
    const float* ln1_w  = (const float*)d_in[1];
    const float* ln1_b  = (const float*)d_in[2];
    const float* w_qkv  = (const float*)d_in[3];
    const float* b_qkv  = (const float*)d_in[4];
    const float* w_proj = (const float*)d_in[5];
    const float* b_proj = (const float*)d_in[6];
    const float* ln2_w  = (const float*)d_in[7];
    const float* ln2_b  = (const float*)d_in[8];
    const float* w_fc1  = (const float*)d_in[9];
    const float* b_fc1  = (const float*)d_in[10];
    const float* w_fc2  = (const float*)d_in[11];
    const float* b_fc2  = (const float*)d_in[12];
    float* out = (float*)d_out;

    char* ws = (char*)d_ws;
    unsigned short* wqkv_bf  = (unsigned short*)(ws);                        // 6 MB (packed)
    unsigned short* wproj_bf = (unsigned short*)(ws + ((size_t)6 << 20));    // 2 MB (packed)
    unsigned short* wfc1_bf  = (unsigned short*)(ws + ((size_t)8 << 20));    // 8 MB (packed)
    unsigned short* wfc2_bf  = (unsigned short*)(ws + ((size_t)16 << 20));   // 8 MB (packed)
    unsigned short* ln_buf   = (unsigned short*)(ws + ((size_t)24 << 20));   // 8 MB
    unsigned short* qkv_bf   = (unsigned short*)(ws + ((size_t)32 << 20));   // 24 MB
    unsigned short* attn_bf  = (unsigned short*)(ws + ((size_t)56 << 20));   // 8 MB
    unsigned short* fc1_bf   = (unsigned short*)(ws + ((size_t)32 << 20));   // 32 MB (qkv/attn dead)

    cast_pack<<<6144, 256, 0, stream>>>(w_qkv, w_proj, w_fc1, w_fc2,
                                        wqkv_bf, wproj_bf, wfc1_bf, wfc2_bf);

    // 1) LN1 -> bf16
    ln_bf16<<<M_ROWS, 256, 0, stream>>>(x, ln1_w, ln1_b, ln_buf);
    // 2) qkv = ln1 @ w_qkv^T + b_qkv   [4096,3072] bf16   (768 blocks)
    gemm_qkv<<<768, 256, 0, stream>>>(ln_buf, wqkv_bf, b_qkv, qkv_bf,
                                      M_ROWS, 3072, 1024);
    // 3) MFMA flash attention -> bf16 [4096,1024]   (512 blocks, paired)
    attn_mfma<<<512, 256, 0, stream>>>(qkv_bf, attn_bf);
    // 4) x1 = x + attn @ w_proj^T + b_proj  -> d_out (fp32)   (512 blocks)
    gemm_proj<<<512, 256, 0, stream>>>(attn_bf, wproj_bf, b_proj, x, out,
                                       M_ROWS, 1024, 1024);
    // 5) LN2 -> bf16
    ln_bf16<<<M_ROWS, 256, 0, stream>>>(out, ln2_w, ln2_b, ln_buf);
    // 6) fc1 + gelu -> bf16 [4096,4096]   (1024 blocks)
    gemm_fc1<<<1024, 256, 0, stream>>>(ln_buf, wfc1_bf, b_fc1, fc1_bf,
                                       M_ROWS, 4096, 1024);
    // 7) out = x1 + fc1 @ w_fc2^T + b_fc2 (in-place residual)   (512 blocks)
    gemm_fc2<<<512, 256, 0, stream>>>(fc1_bf, wfc2_bf, b_fc2, out, out,
                                      M_ROWS, 1024, 4096);
}